// Round 3
// baseline (36.120 us; speedup 1.0000x reference)
//
#include <hip/hip_runtime.h>

#define NH    52
#define NW    52
#define NCLS  80
#define TMAX  50
#define PLANE (NH*NW)    // 2704
#define TAB_F4_PER_B 200 // float4 slots per batch in the ws table

__device__ __forceinline__ float softplus_fast(float x) {
    return fmaxf(x, 0.f) + __logf(1.f + __expf(-fabsf(x)));
}

__device__ __forceinline__ void prep_target(
    int b, int tid, const float* __restrict__ tgt, float4* __restrict__ tab)
{
    const float AW[9] = {1.25f, 2.0f,  4.125f, 3.75f,  7.75f,  7.375f, 14.5f,  19.5f,  46.625f};
    const float AH[9] = {1.625f,3.75f, 2.875f, 7.625f, 5.625f, 14.875f,11.25f, 24.75f, 40.75f};

    float cls = 0.f, x = 0.f, y = 0.f, w = 0.f, h = 0.f;
    if (tid < TMAX) {
        const float* tp = tgt + (size_t)b * (TMAX*5) + tid * 5;
        cls = tp[0]; x = tp[1]; y = tp[2]; w = tp[3]; h = tp[4];
    }
    const unsigned long long m = __ballot((tid < TMAX) ? (x != 0.f) : true);
    if (tid < TMAX) {
        const bool valid = ((~m) & ((2ull << tid) - 1ull)) == 0ull;  // cumprod 0..tid
        float gx = 0.f, gy = 0.f, gw = 0.f, gh = 0.f;
        int   key = -1;
        float txv = 0.f, tyv = 0.f, twv = 0.f, thv = 0.f, csv = 0.f;
        if (valid) {
            gx = x*NW; gy = y*NH; gw = w*NW; gh = h*NH;
            float best = -1.f; int bn = 0;
            #pragma unroll
            for (int n = 0; n < 9; ++n) {
                const float inter = fminf(gw, AW[n]) * fminf(gh, AH[n]);
                const float uni   = gw*gh + AW[n]*AH[n] - inter;
                const float r     = inter / uni;
                if (r > best) { best = r; bn = n; }
            }
            if (bn < 3) {                         // masked anchors 0..2
                const int gi = (int)gx, gj = (int)gy;
                if ((unsigned)gi < NW && (unsigned)gj < NH) {  // scatter mode='drop'
                    key = (bn << 12) | (gj << 6) | gi;
                    txv = gx - (float)gi;
                    tyv = gy - (float)gj;
                    twv = __logf(gw / AW[bn]);
                    thv = __logf(gh / AH[bn]);
                    csv = 2.f - gw*gh * (1.f/(float)PLANE);
                }
            }
        }
        tab[2*tid]       = make_float4(gx - 0.5f*gw, gx + 0.5f*gw, gy - 0.5f*gh, gy + 0.5f*gh);
        tab[2*tid+1]     = make_float4(0.6f*gw*gh, __int_as_float(key), cls, 0.f);
        tab[100+2*tid]   = make_float4(txv, tyv, twv, thv);
        tab[100+2*tid+1] = make_float4(csv, 0.f, 0.f, 0.f);
    }
}

// ---------------- fast path: prep once per batch into d_ws ----------------
__global__ __launch_bounds__(64) void yolo_prep(
    const float* __restrict__ tgt, float4* __restrict__ tab_g, float* __restrict__ out)
{
    const int b = blockIdx.x;
    if (b == 0 && threadIdx.x == 0) out[0] = 0.f;
    prep_target(b, threadIdx.x, tgt, tab_g + (size_t)b * TAB_F4_PER_B);
}

__global__ __launch_bounds__(256) void yolo_main_s(
    const float* __restrict__ inp,   // (32, 255, 52, 52)
    const float4* __restrict__ tab_g,
    float* __restrict__ out)
{
    __shared__ float s_red[4];

    const int tid = threadIdx.x;
    const int ba  = blockIdx.y;      // b*3 + a
    const int b   = ba / 3;
    const int a   = ba % 3;
    const float4* tab = tab_g + (size_t)b * TAB_F4_PER_B;  // wave-uniform -> s_load

    const float AW[9] = {1.25f, 2.0f,  4.125f, 3.75f,  7.75f,  7.375f, 14.5f,  19.5f,  46.625f};
    const float AH[9] = {1.625f,3.75f, 2.875f, 7.625f, 5.625f, 14.875f,11.25f, 24.75f, 40.75f};

    // clamp tail instead of branching: keeps control flow uniform
    const int raw  = blockIdx.x * blockDim.x + tid;
    const bool live = raw < PLANE;
    const int idx  = live ? raw : (PLANE - 1);

    const int i = idx % NW;
    const int j = idx / NW;
    const float* base = inp + ((size_t)b * 255 + (size_t)a * 85) * PLANE + idx;
    const float lx    = base[0];
    const float ly    = base[(size_t)1*PLANE];
    const float lw    = base[(size_t)2*PLANE];
    const float lh    = base[(size_t)3*PLANE];
    const float lconf = base[(size_t)4*PLANE];

    const float sx = __builtin_amdgcn_rcpf(1.f + __expf(-lx));
    const float sy = __builtin_amdgcn_rcpf(1.f + __expf(-ly));
    const float px = sx + (float)i;
    const float py = sy + (float)j;
    const float pw = __expf(lw) * AW[a];
    const float ph = __expf(lh) * AH[a];
    const float pxl = px - 0.5f*pw, pxr = px + 0.5f*pw;
    const float pyl = py - 0.5f*ph, pyr = py + 0.5f*ph;
    const float c06 = 0.6f * (pw * ph);   // 0.6*parea

    bool ignored = false;
    int  hit = -1;                         // last-wins, like sequential scatter
    const int mykey = (a << 12) | (j << 6) | i;

    #pragma unroll 10
    for (int t = 0; t < TMAX; ++t) {
        const float4 A = tab[2*t];
        const float4 B = tab[2*t+1];
        const float cw = fminf(pxr, A.y) - fmaxf(pxl, A.x);
        const float ch = fminf(pyr, A.w) - fmaxf(pyl, A.z);
        const float inter = fmaxf(cw, 0.f) * fmaxf(ch, 0.f);
        // inter/uni > 0.6  <=>  1.6*inter > 0.6*parea + 0.6*garea
        ignored = ignored || (1.6f*inter > c06 + B.x);
        if (__float_as_int(B.y) == mykey) hit = t;
    }

    float acc = 0.f;
    const float tconf = (hit >= 0) ? 1.f : (ignored ? -1.f : 0.f);
    if (tconf != -1.f)
        acc += softplus_fast(lconf) - tconf * lconf;

    if (hit >= 0) {
        const float4 C0 = tab[100 + 2*hit];
        const float4 C1 = tab[100 + 2*hit + 1];
        const float cs = C1.x;
        acc += cs * (softplus_fast(lx) - C0.x * lx);
        acc += cs * (softplus_fast(ly) - C0.y * ly);
        const float dw = lw - C0.z;
        const float dh = lh - C0.w;
        acc += 0.5f * cs * (dw*dw + dh*dh);

        // rebuild class bitmask (rare path: only hit cells)
        unsigned long long cmask0 = 0ull, cmask1 = 0ull;
        for (int t = 0; t < TMAX; ++t) {
            const float4 B = tab[2*t+1];
            if (__float_as_int(B.y) == mykey) {
                const int c = (int)B.z;
                if (c < 64) cmask0 |= (1ull << c);
                else        cmask1 |= (1ull << (c - 64));
            }
        }

        const float* cb = base + (size_t)5 * PLANE;
        if (ignored) {
            for (int c = 0; c < NCLS; ++c) {
                const float l = cb[(size_t)c * PLANE];
                const bool one = (c < 64) ? ((cmask0 >> c) & 1ull)
                                          : ((cmask1 >> (c - 64)) & 1ull);
                acc += softplus_fast(l) - (one ? l : 0.f);
            }
        } else {
            unsigned long long m0 = cmask0, m1 = cmask1;
            while (m0) {
                const int c = __ffsll((unsigned long long)m0) - 1;
                m0 &= (m0 - 1);
                const float l = cb[(size_t)c * PLANE];
                acc += softplus_fast(l) - l;
            }
            while (m1) {
                const int c = __ffsll((unsigned long long)m1) - 1 + 64;
                m1 &= (m1 - 1);
                const float l = cb[(size_t)c * PLANE];
                acc += softplus_fast(l) - l;
            }
        }
    }

    if (!live) acc = 0.f;

    for (int off = 32; off > 0; off >>= 1)
        acc += __shfl_down(acc, off, 64);
    const int wave = tid >> 6;
    const int lane = tid & 63;
    if (lane == 0) s_red[wave] = acc;
    __syncthreads();
    if (tid == 0) {
        float s = s_red[0] + s_red[1] + s_red[2] + s_red[3];
        atomicAdd(out, s);
    }
}

// ---------------- fallback path (round-2 kernel): prep in-block ----------------
__global__ void yolo_zero(float* out) {
    if (threadIdx.x == 0 && blockIdx.x == 0) out[0] = 0.f;
}

__global__ __launch_bounds__(256) void yolo_main_lds(
    const float* __restrict__ inp,
    const float* __restrict__ tgt,
    float* __restrict__ out)
{
    __shared__ float4 s_tab[200];
    __shared__ float  s_red[4];

    const int tid = threadIdx.x;
    const int ba  = blockIdx.y;
    const int b   = ba / 3;
    const int a   = ba % 3;

    const float AW[9] = {1.25f, 2.0f,  4.125f, 3.75f,  7.75f,  7.375f, 14.5f,  19.5f,  46.625f};
    const float AH[9] = {1.625f,3.75f, 2.875f, 7.625f, 5.625f, 14.875f,11.25f, 24.75f, 40.75f};

    if (tid < 64) prep_target(b, tid, tgt, s_tab);
    __syncthreads();

    const int idx = blockIdx.x * blockDim.x + tid;
    float acc = 0.f;
    if (idx < PLANE) {
        const int i = idx % NW;
        const int j = idx / NW;
        const float* base = inp + ((size_t)b * 255 + (size_t)a * 85) * PLANE + idx;
        const float lx    = base[0];
        const float ly    = base[(size_t)1*PLANE];
        const float lw    = base[(size_t)2*PLANE];
        const float lh    = base[(size_t)3*PLANE];
        const float lconf = base[(size_t)4*PLANE];

        const float sx = __builtin_amdgcn_rcpf(1.f + __expf(-lx));
        const float sy = __builtin_amdgcn_rcpf(1.f + __expf(-ly));
        const float px = sx + (float)i;
        const float py = sy + (float)j;
        const float pw = __expf(lw) * AW[a];
        const float ph = __expf(lh) * AH[a];
        const float pxl = px - 0.5f*pw, pxr = px + 0.5f*pw;
        const float pyl = py - 0.5f*ph, pyr = py + 0.5f*ph;
        const float c06 = 0.6f * (pw * ph);

        bool ignored = false;
        int  hit = -1;
        const int mykey = (a << 12) | (j << 6) | i;

        #pragma unroll 5
        for (int t = 0; t < TMAX; ++t) {
            const float4 A = s_tab[2*t];
            const float4 B = s_tab[2*t+1];
            const float cw = fminf(pxr, A.y) - fmaxf(pxl, A.x);
            const float ch = fminf(pyr, A.w) - fmaxf(pyl, A.z);
            const float inter = fmaxf(cw, 0.f) * fmaxf(ch, 0.f);
            ignored = ignored || (1.6f*inter > c06 + B.x);
            if (__float_as_int(B.y) == mykey) hit = t;
        }

        const float tconf = (hit >= 0) ? 1.f : (ignored ? -1.f : 0.f);
        if (tconf != -1.f)
            acc += softplus_fast(lconf) - tconf * lconf;

        if (hit >= 0) {
            const float4 C0 = s_tab[100 + 2*hit];
            const float4 C1 = s_tab[100 + 2*hit + 1];
            const float cs = C1.x;
            acc += cs * (softplus_fast(lx) - C0.x * lx);
            acc += cs * (softplus_fast(ly) - C0.y * ly);
            const float dw = lw - C0.z;
            const float dh = lh - C0.w;
            acc += 0.5f * cs * (dw*dw + dh*dh);

            unsigned long long cmask0 = 0ull, cmask1 = 0ull;
            for (int t = 0; t < TMAX; ++t) {
                const float4 B = s_tab[2*t+1];
                if (__float_as_int(B.y) == mykey) {
                    const int c = (int)B.z;
                    if (c < 64) cmask0 |= (1ull << c);
                    else        cmask1 |= (1ull << (c - 64));
                }
            }

            const float* cb = base + (size_t)5 * PLANE;
            if (ignored) {
                for (int c = 0; c < NCLS; ++c) {
                    const float l = cb[(size_t)c * PLANE];
                    const bool one = (c < 64) ? ((cmask0 >> c) & 1ull)
                                              : ((cmask1 >> (c - 64)) & 1ull);
                    acc += softplus_fast(l) - (one ? l : 0.f);
                }
            } else {
                unsigned long long m0 = cmask0, m1 = cmask1;
                while (m0) {
                    const int c = __ffsll((unsigned long long)m0) - 1;
                    m0 &= (m0 - 1);
                    const float l = cb[(size_t)c * PLANE];
                    acc += softplus_fast(l) - l;
                }
                while (m1) {
                    const int c = __ffsll((unsigned long long)m1) - 1 + 64;
                    m1 &= (m1 - 1);
                    const float l = cb[(size_t)c * PLANE];
                    acc += softplus_fast(l) - l;
                }
            }
        }
    }

    for (int off = 32; off > 0; off >>= 1)
        acc += __shfl_down(acc, off, 64);
    const int wave = tid >> 6;
    const int lane = tid & 63;
    if (lane == 0) s_red[wave] = acc;
    __syncthreads();
    if (tid == 0) {
        float s = s_red[0] + s_red[1] + s_red[2] + s_red[3];
        atomicAdd(out, s);
    }
}

extern "C" void kernel_launch(void* const* d_in, const int* in_sizes, int n_in,
                              void* d_out, int out_size, void* d_ws, size_t ws_size,
                              hipStream_t stream) {
    const float* inp = (const float*)d_in[0];   // (32, 255, 52, 52) f32
    const float* tgt = (const float*)d_in[1];   // (32, 250) f32
    float* out = (float*)d_out;                 // 1 f32

    const size_t tab_bytes = (size_t)32 * TAB_F4_PER_B * sizeof(float4);  // 102400
    dim3 grid((PLANE + 255) / 256, 32 * 3);     // 11 x 96

    if (ws_size >= tab_bytes) {
        float4* tab = (float4*)d_ws;
        yolo_prep<<<dim3(32), dim3(64), 0, stream>>>(tgt, tab, out);
        yolo_main_s<<<grid, dim3(256), 0, stream>>>(inp, tab, out);
    } else {
        yolo_zero<<<dim3(1), dim3(64), 0, stream>>>(out);
        yolo_main_lds<<<grid, dim3(256), 0, stream>>>(inp, tgt, out);
    }
}

// Round 4
// 28.314 us; speedup vs baseline: 1.2757x; 1.2757x over previous
//
#include <hip/hip_runtime.h>

#define NH    52
#define NW    52
#define NCLS  80
#define TMAX  50
#define PLANE (NH*NW)    // 2704

__device__ __forceinline__ float softplus_fast(float x) {
    return fmaxf(x, 0.f) + __logf(1.f + __expf(-fabsf(x)));
}

__global__ void yolo_zero(float* out) {
    if (threadIdx.x == 0 && blockIdx.x == 0) out[0] = 0.f;
}

__global__ __launch_bounds__(256) void yolo_main(
    const float* __restrict__ inp,   // (32, 255, 52, 52)
    const float* __restrict__ tgt,   // (32, 250)
    float* __restrict__ out)
{
    // s_tab: [2t]={gxl,gxr,gyl,gyr} [2t+1]={0.6*garea, key, cls, 0}
    //        [100+2t]={tx,ty,tw,th} [100+2t+1]={coord_scale,0,0,0}
    __shared__ float4 s_tab[200];
    __shared__ float  s_red[4];

    const int tid  = threadIdx.x;
    const int lane = tid & 63;
    const int ba   = blockIdx.y;     // b*3 + a
    const int b    = ba / 3;
    const int a    = ba % 3;

    const float AW[9] = {1.25f, 2.0f,  4.125f, 3.75f,  7.75f,  7.375f, 14.5f,  19.5f,  46.625f};
    const float AH[9] = {1.625f,3.75f, 2.875f, 7.625f, 5.625f, 14.875f,11.25f, 24.75f, 40.75f};

    // ---------- target preprocessing: wave 0 ----------
    if (tid < 64) {
        float cls = 0.f, x = 0.f, y = 0.f, w = 0.f, h = 0.f;
        if (tid < TMAX) {
            const float* tp = tgt + (size_t)b * (TMAX*5) + tid * 5;
            cls = tp[0]; x = tp[1]; y = tp[2]; w = tp[3]; h = tp[4];
        }
        const unsigned long long m = __ballot((tid < TMAX) ? (x != 0.f) : true);
        if (tid < TMAX) {
            const bool valid = ((~m) & ((2ull << tid) - 1ull)) == 0ull;  // cumprod 0..tid
            float gx = 0.f, gy = 0.f, gw = 0.f, gh = 0.f;
            int   key = -1;
            float txv = 0.f, tyv = 0.f, twv = 0.f, thv = 0.f, csv = 0.f;
            if (valid) {
                gx = x*NW; gy = y*NH; gw = w*NW; gh = h*NH;
                float best = -1.f; int bn = 0;
                #pragma unroll
                for (int n = 0; n < 9; ++n) {
                    const float inter = fminf(gw, AW[n]) * fminf(gh, AH[n]);
                    const float uni   = gw*gh + AW[n]*AH[n] - inter;
                    const float r     = inter / uni;
                    if (r > best) { best = r; bn = n; }
                }
                if (bn < 3) {                         // masked anchors 0..2
                    const int gi = (int)gx, gj = (int)gy;
                    if ((unsigned)gi < NW && (unsigned)gj < NH) {  // scatter mode='drop'
                        key = (bn << 12) | (gj << 6) | gi;
                        txv = gx - (float)gi;
                        tyv = gy - (float)gj;
                        twv = __logf(gw / AW[bn]);
                        thv = __logf(gh / AH[bn]);
                        csv = 2.f - gw*gh * (1.f/(float)PLANE);
                    }
                }
            }
            s_tab[2*tid]       = make_float4(gx - 0.5f*gw, gx + 0.5f*gw, gy - 0.5f*gh, gy + 0.5f*gh);
            s_tab[2*tid+1]     = make_float4(0.6f*gw*gh, __int_as_float(key), cls, 0.f);
            s_tab[100+2*tid]   = make_float4(txv, tyv, twv, thv);
            s_tab[100+2*tid+1] = make_float4(csv, 0.f, 0.f, 0.f);
        }
    }
    __syncthreads();

    // ---------- per-cell work (uniform control flow; tail lanes clamped) ----------
    const int raw  = blockIdx.x * blockDim.x + tid;
    const bool live = raw < PLANE;
    const int idx  = live ? raw : (PLANE - 1);

    const int i = idx % NW;
    const int j = idx / NW;
    const float* base = inp + ((size_t)b * 255 + (size_t)a * 85) * PLANE + idx;
    const float lx    = base[0];
    const float ly    = base[(size_t)1*PLANE];
    const float lw    = base[(size_t)2*PLANE];
    const float lh    = base[(size_t)3*PLANE];
    const float lconf = base[(size_t)4*PLANE];

    const float sx = __builtin_amdgcn_rcpf(1.f + __expf(-lx));
    const float sy = __builtin_amdgcn_rcpf(1.f + __expf(-ly));
    const float px = sx + (float)i;
    const float py = sy + (float)j;
    const float pw = __expf(lw) * AW[a];
    const float ph = __expf(lh) * AH[a];
    const float pxl = px - 0.5f*pw, pxr = px + 0.5f*pw;
    const float pyl = py - 0.5f*ph, pyr = py + 0.5f*ph;
    const float c06 = 0.6f * (pw * ph);   // 0.6*parea

    bool ignored = false;
    int  hit = -1;                         // last-wins, like sequential scatter
    const int mykey = (a << 12) | (j << 6) | i;

    #pragma unroll 10
    for (int t = 0; t < TMAX; ++t) {
        const float4 A = s_tab[2*t];
        const float4 B = s_tab[2*t+1];
        const float cw = fminf(pxr, A.y) - fmaxf(pxl, A.x);
        const float ch = fminf(pyr, A.w) - fmaxf(pyl, A.z);
        const float inter = fmaxf(cw, 0.f) * fmaxf(ch, 0.f);
        // inter/uni > 0.6  <=>  1.6*inter > 0.6*parea + 0.6*garea
        ignored = ignored || (1.6f*inter > c06 + B.x);
        if (__float_as_int(B.y) == mykey) hit = t;
    }

    float acc = 0.f;
    const float tconf = (hit >= 0) ? 1.f : (ignored ? -1.f : 0.f);
    if (tconf != -1.f)
        acc += softplus_fast(lconf) - tconf * lconf;

    unsigned long long cmask0 = 0ull, cmask1 = 0ull;
    if (hit >= 0) {
        const float4 C0 = s_tab[100 + 2*hit];
        const float4 C1 = s_tab[100 + 2*hit + 1];
        const float cs = C1.x;
        acc += cs * (softplus_fast(lx) - C0.x * lx);
        acc += cs * (softplus_fast(ly) - C0.y * ly);
        const float dw = lw - C0.z;
        const float dh = lh - C0.w;
        acc += 0.5f * cs * (dw*dw + dh*dh);

        // class bitmask: union over duplicate targets at this cell (rare rescan)
        for (int t = 0; t < TMAX; ++t) {
            const float4 B = s_tab[2*t+1];
            if (__float_as_int(B.y) == mykey) {
                const int c = (int)B.z;
                if (c < 64) cmask0 |= (1ull << c);
                else        cmask1 |= (1ull << (c - 64));
            }
        }
    }

    if (!live) acc = 0.f;

    // ---------- wave-cooperative class loss: parallel loads, no serial chains ----------
    unsigned long long hmask = __ballot(live && (hit >= 0));
    while (hmask) {
        const int src = __ffsll(hmask) - 1;
        hmask &= (hmask - 1);
        const int  sidx  = __shfl(idx, src, 64);
        const int  signd = __shfl((int)ignored, src, 64);
        const unsigned m0lo = (unsigned)__shfl((int)(unsigned)(cmask0      ), src, 64);
        const unsigned m0hi = (unsigned)__shfl((int)(unsigned)(cmask0 >> 32), src, 64);
        const unsigned m1lo = (unsigned)__shfl((int)(unsigned)(cmask1      ), src, 64);

        const float* cbase = inp + ((size_t)b * 255 + (size_t)a * 85 + 5) * PLANE + sidx;
        const bool one0 = (lane < 32) ? ((m0lo >> lane) & 1u) : ((m0hi >> (lane - 32)) & 1u);
        const bool one1 = (lane < 16) && ((m1lo >> lane) & 1u);

        if (signd) {
            // zero-slice applied: all 80 classes participate (parallel across lanes)
            const float l0 = cbase[(size_t)lane * PLANE];
            acc += softplus_fast(l0) - (one0 ? l0 : 0.f);
            if (lane < 16) {
                const float l1 = cbase[(size_t)(64 + lane) * PLANE];
                acc += softplus_fast(l1) - (one1 ? l1 : 0.f);
            }
        } else {
            // only set classes participate
            if (one0) {
                const float l0 = cbase[(size_t)lane * PLANE];
                acc += softplus_fast(l0) - l0;
            }
            if (one1) {
                const float l1 = cbase[(size_t)(64 + lane) * PLANE];
                acc += softplus_fast(l1) - l1;
            }
        }
    }

    // ---------- reduction: wave64 shuffle -> LDS -> one atomic per block ----------
    for (int off = 32; off > 0; off >>= 1)
        acc += __shfl_down(acc, off, 64);
    const int wave = tid >> 6;
    if (lane == 0) s_red[wave] = acc;
    __syncthreads();
    if (tid == 0) {
        float s = s_red[0] + s_red[1] + s_red[2] + s_red[3];
        atomicAdd(out, s);
    }
}

extern "C" void kernel_launch(void* const* d_in, const int* in_sizes, int n_in,
                              void* d_out, int out_size, void* d_ws, size_t ws_size,
                              hipStream_t stream) {
    const float* inp = (const float*)d_in[0];   // (32, 255, 52, 52) f32
    const float* tgt = (const float*)d_in[1];   // (32, 250) f32
    float* out = (float*)d_out;                 // 1 f32

    yolo_zero<<<dim3(1), dim3(64), 0, stream>>>(out);

    dim3 grid((PLANE + 255) / 256, 32 * 3);     // 11 x 96
    yolo_main<<<grid, dim3(256), 0, stream>>>(inp, tgt, out);
}

// Round 5
// 26.090 us; speedup vs baseline: 1.3844x; 1.0852x over previous
//
#include <hip/hip_runtime.h>

#define NH    52
#define NW    52
#define NCLS  80
#define TMAX  50
#define PLANE (NH*NW)     // 2704
#define NBX   11          // ceil(PLANE/256)
#define NBA   96          // 32 batches * 3 anchors
#define NWAVES (NBA*NBX*4)  // 4224 partial-sum slots

__device__ __forceinline__ float softplus_fast(float x) {
    return fmaxf(x, 0.f) + __logf(1.f + __expf(-fabsf(x)));
}
__device__ __forceinline__ float rl_f(float v, int l) {
    return __int_as_float(__builtin_amdgcn_readlane(__float_as_int(v), l));
}
__device__ __forceinline__ int rl_i(int v, int l) {
    return __builtin_amdgcn_readlane(v, l);
}

__global__ void yolo_zero(float* out) {
    if (threadIdx.x == 0 && blockIdx.x == 0) out[0] = 0.f;
}

__global__ __launch_bounds__(256) void yolo_main(
    const float* __restrict__ inp,   // (32, 255, 52, 52)
    const float* __restrict__ tgt,   // (32, 250)
    float* __restrict__ part,        // NWAVES partials (fast path)
    float* __restrict__ out,         // atomic fallback
    int use_atomic)
{
    const int tid  = threadIdx.x;
    const int lane = tid & 63;
    const int wv   = tid >> 6;
    const int ba   = blockIdx.y;     // b*3 + a
    const int b    = ba / 3;
    const int a    = ba % 3;

    const float AW[9] = {1.25f, 2.0f,  4.125f, 3.75f,  7.75f,  7.375f, 14.5f,  19.5f,  46.625f};
    const float AH[9] = {1.625f,3.75f, 2.875f, 7.625f, 5.625f, 14.875f,11.25f, 24.75f, 40.75f};

    // ---------- cell loads issued FIRST (latency hides under prep) ----------
    const int raw  = blockIdx.x * 256 + tid;
    const bool live = raw < PLANE;
    const int idx  = live ? raw : (PLANE - 1);
    const int i = idx % NW;
    const int j = idx / NW;
    const float* base = inp + ((size_t)b * 255 + (size_t)a * 85) * PLANE + idx;
    const float lx    = base[0];
    const float ly    = base[(size_t)1*PLANE];
    const float lw    = base[(size_t)2*PLANE];
    const float lh    = base[(size_t)3*PLANE];
    const float lconf = base[(size_t)4*PLANE];

    // ---------- per-wave target prep: lanes 0..49, no barrier, no LDS ----------
    float gxl=0.f, gxr=0.f, gyl=0.f, gyr=0.f, g06=0.f;
    int   keyv=-1, clsv=0;
    float txv=0.f, tyv=0.f, twv=0.f, thv=0.f, csv=0.f;
    {
        float cls=0.f, x=0.f, y=0.f, w=0.f, h=0.f;
        if (lane < TMAX) {
            const float* tp = tgt + (size_t)b * (TMAX*5) + lane * 5;
            cls = tp[0]; x = tp[1]; y = tp[2]; w = tp[3]; h = tp[4];
        }
        const unsigned long long m = __ballot((lane < TMAX) ? (x != 0.f) : true);
        if (lane < TMAX) {
            const bool valid = ((~m) & ((2ull << lane) - 1ull)) == 0ull;  // cumprod 0..lane
            if (valid) {
                const float gx = x*NW, gy = y*NH, gw = w*NW, gh = h*NH;
                const float garea = gw * gh;
                // argmax over 9 anchors by IoU; cross-multiplied compare (all positive)
                float bi = fminf(gw, AW[0]) * fminf(gh, AH[0]);
                float bu = garea + AW[0]*AH[0] - bi;
                int   bn = 0;
                #pragma unroll
                for (int n = 1; n < 9; ++n) {
                    const float in_ = fminf(gw, AW[n]) * fminf(gh, AH[n]);
                    const float un_ = garea + AW[n]*AH[n] - in_;
                    if (in_ * bu > bi * un_) { bi = in_; bu = un_; bn = n; }
                }
                gxl = gx - 0.5f*gw; gxr = gx + 0.5f*gw;
                gyl = gy - 0.5f*gh; gyr = gy + 0.5f*gh;
                g06 = 0.6f * garea;
                clsv = (int)cls;
                if (bn < 3) {                       // masked anchors 0..2 selected
                    const int gi = (int)gx, gj = (int)gy;
                    if ((unsigned)gi < NW && (unsigned)gj < NH) {  // scatter mode='drop'
                        keyv = (bn << 12) | (gj << 6) | gi;
                        txv = gx - (float)gi;
                        tyv = gy - (float)gj;
                        twv = __logf(gw / AW[bn]);
                        thv = __logf(gh / AH[bn]);
                        csv = 2.f - garea * (1.f/(float)PLANE);
                    }
                }
            }
        }
    }

    // ---------- pred box ----------
    const float sx = __builtin_amdgcn_rcpf(1.f + __expf(-lx));
    const float sy = __builtin_amdgcn_rcpf(1.f + __expf(-ly));
    const float px = sx + (float)i;
    const float py = sy + (float)j;
    const float pw = __expf(lw) * AW[a];
    const float ph = __expf(lh) * AH[a];
    const float pxl = px - 0.5f*pw, pxr = px + 0.5f*pw;
    const float pyl = py - 0.5f*ph, pyr = py + 0.5f*ph;
    const float thr_base = 0.6f * (pw * ph);   // 0.6*parea

    // ---------- 50-target scan: register broadcast via readlane, no DS ----------
    bool ignored = false;
    int  hit = -1;                              // last-wins, like sequential scatter
    const int mykey = (a << 12) | (j << 6) | i;

    #pragma unroll
    for (int t = 0; t < TMAX; ++t) {
        const float A0 = rl_f(gxl, t);
        const float A1 = rl_f(gxr, t);
        const float A2 = rl_f(gyl, t);
        const float A3 = rl_f(gyr, t);
        const float G  = rl_f(g06, t);
        const int   K  = rl_i(keyv, t);
        const float cw = fminf(pxr, A1) - fmaxf(pxl, A0);
        const float ch = fminf(pyr, A3) - fmaxf(pyl, A2);
        const float inter = fmaxf(cw, 0.f) * fmaxf(ch, 0.f);
        // inter/uni > 0.6  <=>  1.6*inter > 0.6*parea + 0.6*garea
        ignored = ignored || (1.6f*inter > thr_base + G);
        if (K == mykey) hit = t;
    }

    float acc = 0.f;
    const float tconf = (hit >= 0) ? 1.f : (ignored ? -1.f : 0.f);
    if (tconf != -1.f)
        acc += softplus_fast(lconf) - tconf * lconf;

    unsigned long long cmask0 = 0ull, cmask1 = 0ull;
    const unsigned long long hb = __ballot(live && (hit >= 0));
    if (hb) {
        // coord losses: fetch hit target's data cross-lane (wave-local shuffles)
        const int hsrc = (hit >= 0) ? hit : 0;
        const float tx_ = __shfl(txv, hsrc, 64);
        const float ty_ = __shfl(tyv, hsrc, 64);
        const float tw_ = __shfl(twv, hsrc, 64);
        const float th_ = __shfl(thv, hsrc, 64);
        const float cs_ = __shfl(csv, hsrc, 64);
        if (hit >= 0) {
            acc += cs_ * (softplus_fast(lx) - tx_ * lx);
            acc += cs_ * (softplus_fast(ly) - ty_ * ly);
            const float dw = lw - tw_;
            const float dh = lh - th_;
            acc += 0.5f * cs_ * (dw*dw + dh*dh);
        }
        // class bitmask: union over duplicate targets at this cell (readlane rescan)
        #pragma unroll
        for (int t = 0; t < TMAX; ++t) {
            const int K = rl_i(keyv, t);
            const int C = rl_i(clsv, t);
            if (hit >= 0 && K == mykey) {
                if (C < 64) cmask0 |= (1ull << C);
                else        cmask1 |= (1ull << (C - 64));
            }
        }
    }

    if (!live) acc = 0.f;

    // ---------- wave-cooperative class loss: parallel loads, no serial chains ----------
    unsigned long long hmask = hb;
    while (hmask) {
        const int src = __ffsll(hmask) - 1;
        hmask &= (hmask - 1);
        const int  sidx  = __shfl(idx, src, 64);
        const int  signd = __shfl((int)ignored, src, 64);
        const unsigned m0lo = (unsigned)__shfl((int)(unsigned)(cmask0      ), src, 64);
        const unsigned m0hi = (unsigned)__shfl((int)(unsigned)(cmask0 >> 32), src, 64);
        const unsigned m1lo = (unsigned)__shfl((int)(unsigned)(cmask1      ), src, 64);

        const float* cbase = inp + ((size_t)b * 255 + (size_t)a * 85 + 5) * PLANE + sidx;
        const bool one0 = (lane < 32) ? ((m0lo >> lane) & 1u) : ((m0hi >> (lane - 32)) & 1u);
        const bool one1 = (lane < 16) && ((m1lo >> lane) & 1u);

        if (signd) {
            const float l0 = cbase[(size_t)lane * PLANE];
            acc += softplus_fast(l0) - (one0 ? l0 : 0.f);
            if (lane < 16) {
                const float l1 = cbase[(size_t)(64 + lane) * PLANE];
                acc += softplus_fast(l1) - (one1 ? l1 : 0.f);
            }
        } else {
            if (one0) {
                const float l0 = cbase[(size_t)lane * PLANE];
                acc += softplus_fast(l0) - l0;
            }
            if (one1) {
                const float l1 = cbase[(size_t)(64 + lane) * PLANE];
                acc += softplus_fast(l1) - l1;
            }
        }
    }

    // ---------- wave reduce -> unique ws slot (no atomics, no barrier) ----------
    for (int off = 32; off > 0; off >>= 1)
        acc += __shfl_down(acc, off, 64);
    if (lane == 0) {
        if (use_atomic) atomicAdd(out, acc);
        else part[(ba * NBX + blockIdx.x) * 4 + wv] = acc;
    }
}

__global__ __launch_bounds__(256) void yolo_reduce(
    const float* __restrict__ part, float* __restrict__ out)
{
    __shared__ float s[4];
    float a = 0.f;
    for (int k = threadIdx.x; k < NWAVES; k += 256) a += part[k];
    for (int off = 32; off > 0; off >>= 1)
        a += __shfl_down(a, off, 64);
    if ((threadIdx.x & 63) == 0) s[threadIdx.x >> 6] = a;
    __syncthreads();
    if (threadIdx.x == 0) out[0] = s[0] + s[1] + s[2] + s[3];
}

extern "C" void kernel_launch(void* const* d_in, const int* in_sizes, int n_in,
                              void* d_out, int out_size, void* d_ws, size_t ws_size,
                              hipStream_t stream) {
    const float* inp = (const float*)d_in[0];   // (32, 255, 52, 52) f32
    const float* tgt = (const float*)d_in[1];   // (32, 250) f32
    float* out = (float*)d_out;                 // 1 f32

    dim3 grid(NBX, NBA);                         // 11 x 96

    if (ws_size >= (size_t)NWAVES * sizeof(float)) {
        float* part = (float*)d_ws;
        yolo_main<<<grid, dim3(256), 0, stream>>>(inp, tgt, part, out, 0);
        yolo_reduce<<<dim3(1), dim3(256), 0, stream>>>(part, out);
    } else {
        yolo_zero<<<dim3(1), dim3(64), 0, stream>>>(out);
        yolo_main<<<grid, dim3(256), 0, stream>>>(inp, tgt, nullptr, out, 1);
    }
}